// Round 4
// baseline (522.802 us; speedup 1.0000x reference)
//
#include <hip/hip_runtime.h>
#include <math.h>

typedef unsigned short u16;
typedef short s16x8 __attribute__((ext_vector_type(8)));
typedef float f32x4 __attribute__((ext_vector_type(4)));
typedef long long ll;

__device__ inline u16 f2bf(float f) {
    unsigned u = __float_as_uint(f);
    u += 0x7fffu + ((u >> 16) & 1u);
    return (u16)(u >> 16);
}
__device__ inline float bf2f(u16 h) { return __uint_as_float(((unsigned)h) << 16); }

// async global->LDS, 16B per lane; LDS dest = wave-uniform base + lane*16
__device__ __forceinline__ void glds16(const u16* g, u16* l) {
    __builtin_amdgcn_global_load_lds(
        (__attribute__((address_space(1))) void*)(void*)g,
        (__attribute__((address_space(3))) void*)l, 16, 0, 0);
}

// ---------------- LayerNorm -> bf16 (one block per row, D=1024) ----------------
__global__ __launch_bounds__(256) void ln_bf16(const float* __restrict__ x,
                                               const float* __restrict__ g,
                                               const float* __restrict__ b,
                                               u16* __restrict__ out, int D) {
    int row = blockIdx.x;
    const float* xr = x + (size_t)row * D;
    int t = threadIdx.x;
    float4 v = ((const float4*)xr)[t];
    float s = v.x + v.y + v.z + v.w;
    __shared__ float sm[4];
    #pragma unroll
    for (int o = 32; o > 0; o >>= 1) s += __shfl_down(s, o, 64);
    int lane = t & 63, wv = t >> 6;
    if (lane == 0) sm[wv] = s;
    __syncthreads();
    float mean = (sm[0] + sm[1] + sm[2] + sm[3]) * (1.0f / 1024.0f);
    float dx = v.x - mean, dy = v.y - mean, dz = v.z - mean, dw = v.w - mean;
    float s2 = dx * dx + dy * dy + dz * dz + dw * dw;
    __syncthreads();
    #pragma unroll
    for (int o = 32; o > 0; o >>= 1) s2 += __shfl_down(s2, o, 64);
    if (lane == 0) sm[wv] = s2;
    __syncthreads();
    float var = (sm[0] + sm[1] + sm[2] + sm[3]) * (1.0f / 1024.0f);
    float rstd = rsqrtf(var + 1e-5f);
    float4 gg = ((const float4*)g)[t], bb = ((const float4*)b)[t];
    ushort4 o4;
    o4.x = f2bf(dx * rstd * gg.x + bb.x);
    o4.y = f2bf(dy * rstd * gg.y + bb.y);
    o4.z = f2bf(dz * rstd * gg.z + bb.z);
    o4.w = f2bf(dw * rstd * gg.w + bb.w);
    ((ushort4*)(out + (size_t)row * D))[t] = o4;
}

// ---------------- combine split-K parts + residual + bias, then LayerNorm ----------------
__global__ __launch_bounds__(256) void combine_ln(
    const float* __restrict__ x, const float* __restrict__ p0,
    const float* __restrict__ p1, const float* __restrict__ ob,
    const float* __restrict__ g, const float* __restrict__ b,
    float* __restrict__ x2, u16* __restrict__ xn2) {
    int row = blockIdx.x;
    int t = threadIdx.x;
    size_t base = (size_t)row * 256;  // float4 units
    float4 v = ((const float4*)x)[base + t];
    float4 a0 = ((const float4*)p0)[base + t];
    float4 a1 = ((const float4*)p1)[base + t];
    float4 ob4 = ((const float4*)ob)[t];
    v.x += a0.x + a1.x + ob4.x;
    v.y += a0.y + a1.y + ob4.y;
    v.z += a0.z + a1.z + ob4.z;
    v.w += a0.w + a1.w + ob4.w;
    ((float4*)x2)[base + t] = v;
    float s = v.x + v.y + v.z + v.w;
    __shared__ float sm[4];
    #pragma unroll
    for (int o = 32; o > 0; o >>= 1) s += __shfl_down(s, o, 64);
    int lane = t & 63, wv = t >> 6;
    if (lane == 0) sm[wv] = s;
    __syncthreads();
    float mean = (sm[0] + sm[1] + sm[2] + sm[3]) * (1.0f / 1024.0f);
    float dx = v.x - mean, dy = v.y - mean, dz = v.z - mean, dw = v.w - mean;
    float s2 = dx * dx + dy * dy + dz * dz + dw * dw;
    __syncthreads();
    #pragma unroll
    for (int o = 32; o > 0; o >>= 1) s2 += __shfl_down(s2, o, 64);
    if (lane == 0) sm[wv] = s2;
    __syncthreads();
    float var = (sm[0] + sm[1] + sm[2] + sm[3]) * (1.0f / 1024.0f);
    float rstd = rsqrtf(var + 1e-5f);
    float4 gg = ((const float4*)g)[t], bb = ((const float4*)b)[t];
    ushort4 o4;
    o4.x = f2bf(dx * rstd * gg.x + bb.x);
    o4.y = f2bf(dy * rstd * gg.y + bb.y);
    o4.z = f2bf(dz * rstd * gg.z + bb.z);
    o4.w = f2bf(dw * rstd * gg.w + bb.w);
    ((ushort4*)(xn2 + (size_t)row * 1024))[t] = o4;
}

// out = x2 + p0 + p1 + b2
__global__ __launch_bounds__(256) void combine_out(
    const float* __restrict__ x2, const float* __restrict__ p0,
    const float* __restrict__ p1, const float* __restrict__ b2,
    float* __restrict__ out) {
    size_t i = (size_t)blockIdx.x * 256 + threadIdx.x;
    int col4 = (int)(i & 255);
    float4 v = ((const float4*)x2)[i];
    float4 a0 = ((const float4*)p0)[i];
    float4 a1 = ((const float4*)p1)[i];
    float4 bb = ((const float4*)b2)[col4];
    v.x += a0.x + a1.x + bb.x;
    v.y += a0.y + a1.y + bb.y;
    v.z += a0.z + a1.z + bb.z;
    v.w += a0.w + a1.w + bb.w;
    ((float4*)out)[i] = v;
}

// ---------------- prep: pack q_b,k_b,v_b -> bcat[3E]; zero den[BN] ----------------
__global__ void prep(const float* __restrict__ qb, const float* __restrict__ kb,
                     const float* __restrict__ vb, float* __restrict__ bcat,
                     float* __restrict__ den, int E, int BN) {
    int i = blockIdx.x * 256 + threadIdx.x;
    if (i < E) {
        bcat[i] = qb[i];
        bcat[E + i] = kb[i];
        bcat[2 * E + i] = vb[i];
    }
    if (i < BN) den[i] = 0.f;
}

// ---------------- transposes ----------------
__global__ __launch_bounds__(256) void transpose_qkv(const float* __restrict__ s0,
                                                     const float* __restrict__ s1,
                                                     const float* __restrict__ s2,
                                                     u16* __restrict__ out, int R, int C) {
    int z = blockIdx.z;
    const float* in = (z == 0) ? s0 : (z == 1) ? s1 : s2;
    out += (size_t)z * C * R;
    __shared__ u16 tile[32][33];
    int tx = threadIdx.x & 31, ty = threadIdx.x >> 5;
    int c0 = blockIdx.x * 32, r0 = blockIdx.y * 32;
    #pragma unroll
    for (int i = 0; i < 32; i += 8)
        tile[ty + i][tx] = f2bf(in[(size_t)(r0 + ty + i) * C + c0 + tx]);
    __syncthreads();
    #pragma unroll
    for (int i = 0; i < 32; i += 8)
        out[(size_t)(c0 + ty + i) * R + r0 + tx] = tile[tx][ty + i];
}

template <typename Tin>
__global__ __launch_bounds__(256) void transpose_bf16(const Tin* __restrict__ in,
                                                      u16* __restrict__ out,
                                                      int R, int C, int ldIn,
                                                      ll sIn, ll sOut) {
    in += (size_t)blockIdx.z * sIn;
    out += (size_t)blockIdx.z * sOut;
    __shared__ u16 tile[32][33];
    int tx = threadIdx.x & 31, ty = threadIdx.x >> 5;
    int c0 = blockIdx.x * 32, r0 = blockIdx.y * 32;
    #pragma unroll
    for (int i = 0; i < 32; i += 8) {
        Tin v = in[(size_t)(r0 + ty + i) * ldIn + c0 + tx];
        if constexpr (sizeof(Tin) == 4) tile[ty + i][tx] = f2bf((float)v);
        else                            tile[ty + i][tx] = (u16)v;
    }
    __syncthreads();
    #pragma unroll
    for (int i = 0; i < 32; i += 8)
        out[(size_t)(c0 + ty + i) * R + r0 + tx] = tile[tx][ty + i];
}

// ---------------- GEMM NT: C[m,n] = sum_k A[m,k]*B[n,k] ----------------
// 256 threads, 128x128 tile, BK=32; staging via global_load_lds (16B/lane).
// LDS layout XOR-swizzled at 16B-chunk granularity:
//   chunk(row, q) = row*4 + ((q + (row>>1)) & 3)    (q = k-chunk 0..3)
// Write side picks each lane's global (row, q') so lane L lands at chunk
// waveBase + L; read side computes the swizzled chunk -> all 8 bank-groups
// hit 2 lanes/bank (free) instead of 4-8-way aliasing.
enum { EPI_QKV = 0, EPI_TRIL = 2, EPI_DIV = 3, EPI_GELU = 5, EPI_PART = 6 };

#define TM 128
#define TN 128
#define BK 32

template <int EPI>
__global__ __launch_bounds__(256) void gemm_nt(
    const u16* __restrict__ A, const u16* __restrict__ B, void* __restrict__ Cv,
    const float* __restrict__ bias, float* __restrict__ den,
    int M, int N, int K, int lda, int ldb, int triK,
    ll sA, ll sB, ll sC, ll sAux) {
    int z = blockIdx.z;
    A += (size_t)z * sA;
    B += (size_t)z * sB;

    // panel-of-4 swizzle (gridDim.y % 4 == 0 for all our launches)
    int nb = gridDim.x;
    int bl = blockIdx.y * nb + blockIdx.x;
    int panel = nb * 4;
    int pp = bl / panel, rr = bl - pp * panel;
    int m0 = (pp * 4 + (rr & 3)) * TM;
    int n0 = (rr >> 2) * TN;

    int t = threadIdx.x;

    // strictly-above-diagonal tril blocks: never written, never read downstream
    if (EPI == EPI_TRIL && n0 > m0 + (TM - 1)) return;

    __shared__ __align__(16) u16 As[TM * BK];
    __shared__ __align__(16) u16 Bs[TN * BK];

    f32x4 acc[4][4];
    #pragma unroll
    for (int i = 0; i < 4; i++)
        #pragma unroll
        for (int j = 0; j < 4; j++) { f32x4 zz = {0.f, 0.f, 0.f, 0.f}; acc[i][j] = zz; }

    int kend = (EPI == EPI_DIV && triK) ? (m0 + TM < K ? m0 + TM : K) : K;

    int lane = t & 63, wv = t >> 6;
    int lr = lane & 15, q = lane >> 4;
    int wm = (wv & 1) * 64, wn = (wv >> 1) * 64;

    // ---- staging addresses (swizzle-aware) ----
    // lane L -> chunk wv*128 + L; row = wv*32 + (L>>2); need (q' + (row>>1))&3 == L&3
    int srow = wv * 32 + (lane >> 2);
    int sq = ((lane & 3) - ((lane >> 3) & 3)) & 3;   // q' for this lane (rows +0 and +16 agree)
    int skf = sq * 8;
    const u16* gA0 = A + (size_t)(m0 + srow) * lda + skf;
    const u16* gA1 = gA0 + (size_t)16 * lda;
    const u16* gB0 = B + (size_t)(n0 + srow) * ldb + skf;
    const u16* gB1 = gB0 + (size_t)16 * ldb;
    u16* lA = As + wv * 32 * BK;  // wave-uniform LDS base
    u16* lB = Bs + wv * 32 * BK;

    // ---- fragment read offsets (u16 units), swizzled chunk -> *8 ----
    int ca[4], cb[4];
    #pragma unroll
    for (int i = 0; i < 4; i++) {
        int ra = wm + i * 16 + lr;
        ca[i] = (ra * 4 + ((q + (ra >> 1)) & 3)) * 8;
        int rb = wn + i * 16 + lr;
        cb[i] = (rb * 4 + ((q + (rb >> 1)) & 3)) * 8;
    }

    for (int k0 = 0; k0 < kend; k0 += BK) {
        glds16(gA0 + k0, lA);
        glds16(gA1 + k0, lA + 16 * BK);
        glds16(gB0 + k0, lB);
        glds16(gB1 + k0, lB + 16 * BK);
        __syncthreads();  // drains vmcnt -> LDS tiles ready
        s16x8 af[4], bfr[4];
        #pragma unroll
        for (int i = 0; i < 4; i++) af[i] = *(const s16x8*)&As[ca[i]];
        #pragma unroll
        for (int j = 0; j < 4; j++) bfr[j] = *(const s16x8*)&Bs[cb[j]];
        #pragma unroll
        for (int i = 0; i < 4; i++)
            #pragma unroll
            for (int j = 0; j < 4; j++)
                acc[i][j] = __builtin_amdgcn_mfma_f32_16x16x32_bf16(af[i], bfr[j], acc[i][j], 0, 0, 0);
        __syncthreads();  // protect LDS from next iteration's overwrite
    }

    u16* Cb = (u16*)Cv + (size_t)z * sC;
    float* Cf = (float*)Cv + (size_t)z * sC;
    bool isQK = (EPI == EPI_QKV) && (n0 < 4096);  // block-uniform
    #pragma unroll
    for (int i = 0; i < 4; i++) {
        #pragma unroll
        for (int r = 0; r < 4; r++) {
            int row = m0 + wm + i * 16 + q * 4 + r;
            float rs = 0.f;
            #pragma unroll
            for (int j = 0; j < 4; j++) {
                int col = n0 + wn + j * 16 + lr;
                float v = acc[i][j][r];
                if (EPI == EPI_QKV) {
                    v += bias[col];
                    if (isQK) v = (v > 0.f) ? (v + 1.f) : __expf(v);  // elu+1
                    Cb[(size_t)row * N + col] = f2bf(v);
                } else if (EPI == EPI_TRIL) {
                    v = (col <= row) ? v : 0.f;
                    rs += v;
                    Cb[(size_t)row * N + col] = f2bf(v);
                } else if (EPI == EPI_DIV) {
                    float d = den[(size_t)z * sAux + row] + 1e-6f;
                    Cb[(size_t)row * N + col] = f2bf(v / d);
                } else if (EPI == EPI_GELU) {
                    v += bias[col];
                    // gelu(v) ~ v * sigmoid(2u), u = 0.79788456*(v + 0.044715 v^3)
                    float u = v * (0.7978845608f + 0.0356774081f * v * v);
                    u = fminf(u, 40.f);
                    float e = __expf(2.f * u);
                    v = v * __fdividef(e, e + 1.f);
                    Cb[(size_t)row * N + col] = f2bf(v);
                } else if (EPI == EPI_PART) {
                    Cf[(size_t)row * N + col] = v;
                }
            }
            if (EPI == EPI_TRIL) {
                // reduce rs over the 16 lanes (lr) of this q-group -> row sum of 64 cols
                #pragma unroll
                for (int m = 1; m < 16; m <<= 1) rs += __shfl_xor(rs, m, 16);
                if (lr == 0) atomicAdd(&den[(size_t)z * sAux + row], rs);
            }
        }
    }
}

extern "C" void kernel_launch(void* const* d_in, const int* in_sizes, int n_in,
                              void* d_out, int out_size, void* d_ws, size_t ws_size,
                              hipStream_t stream) {
    const float* x    = (const float*)d_in[0];
    const float* q_w  = (const float*)d_in[1];
    const float* q_b  = (const float*)d_in[2];
    const float* k_w  = (const float*)d_in[3];
    const float* k_b  = (const float*)d_in[4];
    const float* v_w  = (const float*)d_in[5];
    const float* v_b  = (const float*)d_in[6];
    const float* o_w  = (const float*)d_in[7];
    const float* o_b  = (const float*)d_in[8];
    const float* ln1g = (const float*)d_in[9];
    const float* ln1b = (const float*)d_in[10];
    const float* ln2g = (const float*)d_in[11];
    const float* ln2b = (const float*)d_in[12];
    const float* w1   = (const float*)d_in[13];
    const float* b1   = (const float*)d_in[14];
    const float* w2   = (const float*)d_in[15];
    const float* b2   = (const float*)d_in[16];
    float* out = (float*)d_out;

    constexpr int Bb = 2, N = 2048, D = 1024, E = 2048, F = 4096;
    constexpr int BN = Bb * N;     // 4096
    constexpr int E3 = 3 * E;      // 6144

    char* ws = (char*)d_ws;
    size_t off = 0;
    auto alloc = [&](size_t bytes) -> void* {
        void* p = ws + off;
        off += (bytes + 255) & ~(size_t)255;
        return p;
    };
    u16*   qkvT = (u16*)alloc((size_t)E3 * D * 2);     // 12 MB
    u16*   oT   = (u16*)alloc((size_t)D * E * 2);      // 4 MB
    u16*   w1T  = (u16*)alloc((size_t)F * D * 2);      // 8 MB
    u16*   w2T  = (u16*)alloc((size_t)D * F * 2);      // 8 MB
    float* bcat = (float*)alloc((size_t)E3 * 4);
    u16*   xn   = (u16*)alloc((size_t)BN * D * 2);     // 8 MB (reused as xn2)
    u16*   QKV  = (u16*)alloc((size_t)BN * E3 * 2);    // 48 MB (reused: P, h)
    u16*   Vt   = (u16*)alloc((size_t)Bb * E * N * 2); // 16 MB (reused as x2 fp32)
    u16*   Amat = (u16*)alloc((size_t)Bb * N * N * 2); // 32 MB (reused as parts)
    float* den  = (float*)alloc((size_t)BN * 4);

    u16*   xn2 = xn;
    u16*   P   = QKV;                  // [BN,E] bf16
    u16*   h   = QKV + (size_t)8 * 1024 * 1024;  // [BN,F] bf16
    float* x2  = (float*)Vt;           // [BN,D] fp32
    float* pt0 = (float*)Amat;         // split-K partial 0
    float* pt1 = pt0 + (size_t)BN * D; // split-K partial 1

    dim3 blk(256);

    // ---- prep: biases + den zero ----
    prep<<<dim3((BN + 255) / 256), blk, 0, stream>>>(q_b, k_b, v_b, bcat, den, E, BN);

    // ---- weight transposes ----
    transpose_qkv<<<dim3(E / 32, D / 32, 3), blk, 0, stream>>>(q_w, k_w, v_w, qkvT, D, E);
    transpose_bf16<float><<<dim3(D / 32, E / 32, 1), blk, 0, stream>>>(o_w, oT, E, D, D, 0, 0);
    transpose_bf16<float><<<dim3(F / 32, D / 32, 1), blk, 0, stream>>>(w1, w1T, D, F, F, 0, 0);
    transpose_bf16<float><<<dim3(D / 32, F / 32, 1), blk, 0, stream>>>(w2, w2T, F, D, D, 0, 0);

    // ---- LN1 ----
    ln_bf16<<<BN, blk, 0, stream>>>(x, ln1g, ln1b, xn, D);

    // ---- fused QKV projection: [BN,3E], elu+1 on Q,K cols ----
    gemm_nt<EPI_QKV><<<dim3(E3 / 128, BN / 128, 1), blk, 0, stream>>>(
        xn, qkvT, QKV, bcat, nullptr, BN, E3, D, D, D, 0, 0, 0, 0, 0);

    // ---- V^T per batch: [N,E] (stride 3E) -> [E,N] ----
    transpose_bf16<u16><<<dim3(E / 32, N / 32, Bb), blk, 0, stream>>>(
        QKV + 2 * E, Vt, N, E, E3, (ll)N * E3, (ll)E * N);

    // ---- A = tril(Q K^T) per batch, fused rowsum -> den ----
    gemm_nt<EPI_TRIL><<<dim3(N / 128, N / 128, Bb), blk, 0, stream>>>(
        QKV, QKV + E, Amat, nullptr, den, N, N, E, E3, E3, 0,
        (ll)N * E3, (ll)N * E3, (ll)N * N, (ll)N);

    // ---- P = (A @ V) / den (triangular K-loop) ----
    gemm_nt<EPI_DIV><<<dim3(E / 128, N / 128, Bb), blk, 0, stream>>>(
        Amat, Vt, P, nullptr, den, N, E, N, N, N, 1,
        (ll)N * N, (ll)E * N, (ll)N * E, (ll)N);

    // ---- split-K=2: parts = P @ o_w (fp32) ----
    gemm_nt<EPI_PART><<<dim3(D / 128, BN / 128, 2), blk, 0, stream>>>(
        P, oT, pt0, nullptr, nullptr, BN, D, E / 2, E, E, 0,
        (ll)(E / 2), (ll)(E / 2), (ll)BN * D, 0);

    // ---- x2 = x + p0 + p1 + o_b ; xn2 = LN2(x2) ----
    combine_ln<<<BN, blk, 0, stream>>>(x, pt0, pt1, o_b, ln2g, ln2b, x2, xn2);

    // ---- h = gelu(xn2 @ w1 + b1) ----
    gemm_nt<EPI_GELU><<<dim3(F / 128, BN / 128, 1), blk, 0, stream>>>(
        xn2, w1T, h, b1, nullptr, BN, F, D, D, D, 0, 0, 0, 0, 0);

    // ---- split-K=2: parts = h @ w2 (fp32) ----
    gemm_nt<EPI_PART><<<dim3(D / 128, BN / 128, 2), blk, 0, stream>>>(
        h, w2T, pt0, nullptr, nullptr, BN, D, F / 2, F, F, 0,
        (ll)(F / 2), (ll)(F / 2), (ll)BN * D, 0);

    // ---- out = x2 + p0 + p1 + b2 ----
    combine_out<<<dim3(BN * D / 4 / 256), blk, 0, stream>>>(x2, pt0, pt1, b2, out);
}

// Round 6
// 485.714 us; speedup vs baseline: 1.0764x; 1.0764x over previous
//
#include <hip/hip_runtime.h>
#include <math.h>

typedef unsigned short u16;
typedef short s16x8 __attribute__((ext_vector_type(8)));
typedef float f32x4 __attribute__((ext_vector_type(4)));
typedef long long ll;

__device__ inline u16 f2bf(float f) {
    unsigned u = __float_as_uint(f);
    u += 0x7fffu + ((u >> 16) & 1u);
    return (u16)(u >> 16);
}
__device__ inline float bf2f(u16 h) { return __uint_as_float(((unsigned)h) << 16); }

// async global->LDS, 16B per lane; LDS dest = wave-uniform base + lane*16
__device__ __forceinline__ void glds16(const u16* g, u16* l) {
    __builtin_amdgcn_global_load_lds(
        (__attribute__((address_space(1))) void*)(void*)g,
        (__attribute__((address_space(3))) void*)l, 16, 0, 0);
}

// ---------------- LayerNorm -> bf16 (one block per row, D=1024) ----------------
__global__ __launch_bounds__(256) void ln_bf16(const float* __restrict__ x,
                                               const float* __restrict__ g,
                                               const float* __restrict__ b,
                                               u16* __restrict__ out, int D) {
    int row = blockIdx.x;
    const float* xr = x + (size_t)row * D;
    int t = threadIdx.x;
    float4 v = ((const float4*)xr)[t];
    float s = v.x + v.y + v.z + v.w;
    __shared__ float sm[4];
    #pragma unroll
    for (int o = 32; o > 0; o >>= 1) s += __shfl_down(s, o, 64);
    int lane = t & 63, wv = t >> 6;
    if (lane == 0) sm[wv] = s;
    __syncthreads();
    float mean = (sm[0] + sm[1] + sm[2] + sm[3]) * (1.0f / 1024.0f);
    float dx = v.x - mean, dy = v.y - mean, dz = v.z - mean, dw = v.w - mean;
    float s2 = dx * dx + dy * dy + dz * dz + dw * dw;
    __syncthreads();
    #pragma unroll
    for (int o = 32; o > 0; o >>= 1) s2 += __shfl_down(s2, o, 64);
    if (lane == 0) sm[wv] = s2;
    __syncthreads();
    float var = (sm[0] + sm[1] + sm[2] + sm[3]) * (1.0f / 1024.0f);
    float rstd = rsqrtf(var + 1e-5f);
    float4 gg = ((const float4*)g)[t], bb = ((const float4*)b)[t];
    ushort4 o4;
    o4.x = f2bf(dx * rstd * gg.x + bb.x);
    o4.y = f2bf(dy * rstd * gg.y + bb.y);
    o4.z = f2bf(dz * rstd * gg.z + bb.z);
    o4.w = f2bf(dw * rstd * gg.w + bb.w);
    ((ushort4*)(out + (size_t)row * D))[t] = o4;
}

// ---------------- combine split-K parts + residual + bias, then LayerNorm ----------------
__global__ __launch_bounds__(256) void combine_ln(
    const float* __restrict__ x, const float* __restrict__ p0,
    const float* __restrict__ p1, const float* __restrict__ ob,
    const float* __restrict__ g, const float* __restrict__ b,
    float* __restrict__ x2, u16* __restrict__ xn2) {
    int row = blockIdx.x;
    int t = threadIdx.x;
    size_t base = (size_t)row * 256;  // float4 units
    float4 v = ((const float4*)x)[base + t];
    float4 a0 = ((const float4*)p0)[base + t];
    float4 a1 = ((const float4*)p1)[base + t];
    float4 ob4 = ((const float4*)ob)[t];
    v.x += a0.x + a1.x + ob4.x;
    v.y += a0.y + a1.y + ob4.y;
    v.z += a0.z + a1.z + ob4.z;
    v.w += a0.w + a1.w + ob4.w;
    ((float4*)x2)[base + t] = v;
    float s = v.x + v.y + v.z + v.w;
    __shared__ float sm[4];
    #pragma unroll
    for (int o = 32; o > 0; o >>= 1) s += __shfl_down(s, o, 64);
    int lane = t & 63, wv = t >> 6;
    if (lane == 0) sm[wv] = s;
    __syncthreads();
    float mean = (sm[0] + sm[1] + sm[2] + sm[3]) * (1.0f / 1024.0f);
    float dx = v.x - mean, dy = v.y - mean, dz = v.z - mean, dw = v.w - mean;
    float s2 = dx * dx + dy * dy + dz * dz + dw * dw;
    __syncthreads();
    #pragma unroll
    for (int o = 32; o > 0; o >>= 1) s2 += __shfl_down(s2, o, 64);
    if (lane == 0) sm[wv] = s2;
    __syncthreads();
    float var = (sm[0] + sm[1] + sm[2] + sm[3]) * (1.0f / 1024.0f);
    float rstd = rsqrtf(var + 1e-5f);
    float4 gg = ((const float4*)g)[t], bb = ((const float4*)b)[t];
    ushort4 o4;
    o4.x = f2bf(dx * rstd * gg.x + bb.x);
    o4.y = f2bf(dy * rstd * gg.y + bb.y);
    o4.z = f2bf(dz * rstd * gg.z + bb.z);
    o4.w = f2bf(dw * rstd * gg.w + bb.w);
    ((ushort4*)(xn2 + (size_t)row * 1024))[t] = o4;
}

// out = x2 + p0 + p1 + b2
__global__ __launch_bounds__(256) void combine_out(
    const float* __restrict__ x2, const float* __restrict__ p0,
    const float* __restrict__ p1, const float* __restrict__ b2,
    float* __restrict__ out) {
    size_t i = (size_t)blockIdx.x * 256 + threadIdx.x;
    int col4 = (int)(i & 255);
    float4 v = ((const float4*)x2)[i];
    float4 a0 = ((const float4*)p0)[i];
    float4 a1 = ((const float4*)p1)[i];
    float4 bb = ((const float4*)b2)[col4];
    v.x += a0.x + a1.x + bb.x;
    v.y += a0.y + a1.y + bb.y;
    v.z += a0.z + a1.z + bb.z;
    v.w += a0.w + a1.w + bb.w;
    ((float4*)out)[i] = v;
}

// ---------------- prep: pack q_b,k_b,v_b -> bcat[3E]; zero den[BN] ----------------
__global__ void prep(const float* __restrict__ qb, const float* __restrict__ kb,
                     const float* __restrict__ vb, float* __restrict__ bcat,
                     float* __restrict__ den, int E, int BN) {
    int i = blockIdx.x * 256 + threadIdx.x;
    if (i < E) {
        bcat[i] = qb[i];
        bcat[E + i] = kb[i];
        bcat[2 * E + i] = vb[i];
    }
    if (i < BN) den[i] = 0.f;
}

// ---------------- transposes ----------------
__global__ __launch_bounds__(256) void transpose_qkv(const float* __restrict__ s0,
                                                     const float* __restrict__ s1,
                                                     const float* __restrict__ s2,
                                                     u16* __restrict__ out, int R, int C) {
    int z = blockIdx.z;
    const float* in = (z == 0) ? s0 : (z == 1) ? s1 : s2;
    out += (size_t)z * C * R;
    __shared__ u16 tile[32][33];
    int tx = threadIdx.x & 31, ty = threadIdx.x >> 5;
    int c0 = blockIdx.x * 32, r0 = blockIdx.y * 32;
    #pragma unroll
    for (int i = 0; i < 32; i += 8)
        tile[ty + i][tx] = f2bf(in[(size_t)(r0 + ty + i) * C + c0 + tx]);
    __syncthreads();
    #pragma unroll
    for (int i = 0; i < 32; i += 8)
        out[(size_t)(c0 + ty + i) * R + r0 + tx] = tile[tx][ty + i];
}

template <typename Tin>
__global__ __launch_bounds__(256) void transpose_bf16(const Tin* __restrict__ in,
                                                      u16* __restrict__ out,
                                                      int R, int C, int ldIn,
                                                      ll sIn, ll sOut) {
    in += (size_t)blockIdx.z * sIn;
    out += (size_t)blockIdx.z * sOut;
    __shared__ u16 tile[32][33];
    int tx = threadIdx.x & 31, ty = threadIdx.x >> 5;
    int c0 = blockIdx.x * 32, r0 = blockIdx.y * 32;
    #pragma unroll
    for (int i = 0; i < 32; i += 8) {
        Tin v = in[(size_t)(r0 + ty + i) * ldIn + c0 + tx];
        if constexpr (sizeof(Tin) == 4) tile[ty + i][tx] = f2bf((float)v);
        else                            tile[ty + i][tx] = (u16)v;
    }
    __syncthreads();
    #pragma unroll
    for (int i = 0; i < 32; i += 8)
        out[(size_t)(c0 + ty + i) * R + r0 + tx] = tile[tx][ty + i];
}

// ---------------- GEMM NT: C[m,n] = sum_k A[m,k]*B[n,k] ----------------
// 256 threads, 128x128 tile; BKt = 32 or 64; staging via global_load_lds.
// LDS XOR-swizzled at 16B-chunk granularity:
//   BKt=32 (4 chunks/row): chunk(r,q) = r*4 + ((q + (r>>1)) & 3)
//   BKt=64 (8 chunks/row): chunk(r,q) = r*8 + ((q + (r&7)) & 7)
// Both give 2 lanes/bank-group on every ds_read_b128 (free) and keep the
// global_load_lds "base + lane*16" write contiguous.
enum { EPI_QKV = 0, EPI_TRIL = 2, EPI_DIV = 3, EPI_GELU = 5, EPI_PART = 6 };

#define TM 128
#define TN 128

template <int EPI, int BKt>
__global__ __launch_bounds__(256) void gemm_nt(
    const u16* __restrict__ A, const u16* __restrict__ B, void* __restrict__ Cv,
    const float* __restrict__ bias, float* __restrict__ den,
    int M, int N, int K, int lda, int ldb,
    ll sA, ll sB, ll sC, ll sAux) {
    int z = blockIdx.z;
    A += (size_t)z * sA;
    B += (size_t)z * sB;

    // panel-of-4 swizzle (gridDim.y % 4 == 0 for all our launches)
    int nb = gridDim.x;
    int bl = blockIdx.y * nb + blockIdx.x;
    int panel = nb * 4;
    int pp = bl / panel, rr = bl - pp * panel;
    int m0 = (pp * 4 + (rr & 3)) * TM;
    int n0 = (rr >> 2) * TN;

    int t = threadIdx.x;

    // strictly-above-diagonal tril blocks: write zeros (keeps Amat fully
    // defined in-call; the region aliases split-K partials of prior calls)
    if (EPI == EPI_TRIL && n0 > m0 + (TM - 1)) {
        u16* C = (u16*)Cv + (size_t)z * sC;
        #pragma unroll
        for (int s = 0; s < 8; ++s) {
            int v = t + 256 * s;          // 0..2047
            int row = v >> 4, cf = (v & 15) * 8;
            *(uint4*)&C[(size_t)(m0 + row) * N + n0 + cf] = make_uint4(0, 0, 0, 0);
        }
        return;
    }

    __shared__ __align__(16) u16 As[TM * BKt];
    __shared__ __align__(16) u16 Bs[TN * BKt];

    f32x4 acc[4][4];
    #pragma unroll
    for (int i = 0; i < 4; i++)
        #pragma unroll
        for (int j = 0; j < 4; j++) { f32x4 zz = {0.f, 0.f, 0.f, 0.f}; acc[i][j] = zz; }

    int kend = (EPI == EPI_DIV) ? (m0 + TM < K ? m0 + TM : K) : K;

    int lane = t & 63, wv = t >> 6;
    int lr = lane & 15, q = lane >> 4;
    int wm = (wv & 1) * 64, wn = (wv >> 1) * 64;

    u16* lA = As + wv * 32 * BKt;  // wave-uniform LDS base (32 rows per wave)
    u16* lB = Bs + wv * 32 * BKt;

    // ---- staging addresses (swizzle-aware) ----
    int srow, skf;
    if (BKt == 32) {
        srow = wv * 32 + (lane >> 2);
        skf = (((lane & 3) - ((lane >> 3) & 3)) & 3) * 8;
    } else {
        srow = wv * 32 + (lane >> 3);
        skf = (((lane & 7) - (lane >> 3)) & 7) * 8;
    }
    const u16* gA0 = A + (size_t)(m0 + srow) * lda + skf;
    const u16* gB0 = B + (size_t)(n0 + srow) * ldb + skf;

    // ---- fragment read offsets (u16 units) ----
    int ca[2][4], cb[2][4];
    #pragma unroll
    for (int i = 0; i < 4; i++) {
        int ra = wm + i * 16 + lr;
        int rb = wn + i * 16 + lr;
        if (BKt == 32) {
            ca[0][i] = (ra * 4 + ((q + (ra >> 1)) & 3)) * 8;
            cb[0][i] = (rb * 4 + ((q + (rb >> 1)) & 3)) * 8;
        } else {
            ca[0][i] = (ra * 8 + ((q + (ra & 7)) & 7)) * 8;
            ca[1][i] = (ra * 8 + ((4 + q + (ra & 7)) & 7)) * 8;
            cb[0][i] = (rb * 8 + ((q + (rb & 7)) & 7)) * 8;
            cb[1][i] = (rb * 8 + ((4 + q + (rb & 7)) & 7)) * 8;
        }
    }

    for (int k0 = 0; k0 < kend; k0 += BKt) {
        if (BKt == 32) {
            glds16(gA0 + k0, lA);
            glds16(gA0 + k0 + (size_t)16 * lda, lA + 16 * BKt);
            glds16(gB0 + k0, lB);
            glds16(gB0 + k0 + (size_t)16 * ldb, lB + 16 * BKt);
        } else {
            #pragma unroll
            for (int r = 0; r < 4; ++r) {
                glds16(gA0 + k0 + (size_t)(8 * r) * lda, lA + r * 8 * BKt);
                glds16(gB0 + k0 + (size_t)(8 * r) * ldb, lB + r * 8 * BKt);
            }
        }
        __syncthreads();  // drains vmcnt -> LDS tiles ready
        #pragma unroll
        for (int kk = 0; kk < BKt / 32; ++kk) {
            s16x8 af[4], bfr[4];
            #pragma unroll
            for (int i = 0; i < 4; i++) af[i] = *(const s16x8*)&As[ca[kk][i]];
            #pragma unroll
            for (int j = 0; j < 4; j++) bfr[j] = *(const s16x8*)&Bs[cb[kk][j]];
            #pragma unroll
            for (int i = 0; i < 4; i++)
                #pragma unroll
                for (int j = 0; j < 4; j++)
                    acc[i][j] = __builtin_amdgcn_mfma_f32_16x16x32_bf16(af[i], bfr[j], acc[i][j], 0, 0, 0);
        }
        __syncthreads();  // protect LDS from next iteration's overwrite
    }

    u16* Cb = (u16*)Cv + (size_t)z * sC;
    float* Cf = (float*)Cv + (size_t)z * sC;
    bool isQK = (EPI == EPI_QKV) && (n0 < 4096);  // block-uniform
    #pragma unroll
    for (int i = 0; i < 4; i++) {
        #pragma unroll
        for (int r = 0; r < 4; r++) {
            int row = m0 + wm + i * 16 + q * 4 + r;
            float rs = 0.f;
            #pragma unroll
            for (int j = 0; j < 4; j++) {
                int col = n0 + wn + j * 16 + lr;
                float v = acc[i][j][r];
                if (EPI == EPI_QKV) {
                    v += bias[col];
                    if (isQK) v = (v > 0.f) ? (v + 1.f) : __expf(v);  // elu+1
                    Cb[(size_t)row * N + col] = f2bf(v);
                } else if (EPI == EPI_TRIL) {
                    v = (col <= row) ? v : 0.f;
                    rs += v;
                    Cb[(size_t)row * N + col] = f2bf(v);
                } else if (EPI == EPI_DIV) {
                    float d = den[(size_t)z * sAux + row] + 1e-6f;
                    Cb[(size_t)row * N + col] = f2bf(v / d);
                } else if (EPI == EPI_GELU) {
                    v += bias[col];
                    // gelu(v) ~ v * sigmoid(2u), u = 0.79788456*(v + 0.044715 v^3)
                    float u = v * (0.7978845608f + 0.0356774081f * v * v);
                    u = fminf(u, 40.f);
                    float e = __expf(2.f * u);
                    v = v * __fdividef(e, e + 1.f);
                    Cb[(size_t)row * N + col] = f2bf(v);
                } else if (EPI == EPI_PART) {
                    Cf[(size_t)row * N + col] = v;
                }
            }
            if (EPI == EPI_TRIL) {
                // reduce rs over the 16 lanes (lr) of this q-group -> row sum of 64 cols
                #pragma unroll
                for (int m = 1; m < 16; m <<= 1) rs += __shfl_xor(rs, m, 16);
                if (lr == 0) atomicAdd(&den[(size_t)z * sAux + row], rs);
            }
        }
    }
}

extern "C" void kernel_launch(void* const* d_in, const int* in_sizes, int n_in,
                              void* d_out, int out_size, void* d_ws, size_t ws_size,
                              hipStream_t stream) {
    const float* x    = (const float*)d_in[0];
    const float* q_w  = (const float*)d_in[1];
    const float* q_b  = (const float*)d_in[2];
    const float* k_w  = (const float*)d_in[3];
    const float* k_b  = (const float*)d_in[4];
    const float* v_w  = (const float*)d_in[5];
    const float* v_b  = (const float*)d_in[6];
    const float* o_w  = (const float*)d_in[7];
    const float* o_b  = (const float*)d_in[8];
    const float* ln1g = (const float*)d_in[9];
    const float* ln1b = (const float*)d_in[10];
    const float* ln2g = (const float*)d_in[11];
    const float* ln2b = (const float*)d_in[12];
    const float* w1   = (const float*)d_in[13];
    const float* b1   = (const float*)d_in[14];
    const float* w2   = (const float*)d_in[15];
    const float* b2   = (const float*)d_in[16];
    float* out = (float*)d_out;

    constexpr int Bb = 2, N = 2048, D = 1024, E = 2048, F = 4096;
    constexpr int BN = Bb * N;     // 4096
    constexpr int E3 = 3 * E;      // 6144

    char* ws = (char*)d_ws;
    size_t off = 0;
    auto alloc = [&](size_t bytes) -> void* {
        void* p = ws + off;
        off += (bytes + 255) & ~(size_t)255;
        return p;
    };
    u16*   qkvT = (u16*)alloc((size_t)E3 * D * 2);     // 12 MB
    u16*   oT   = (u16*)alloc((size_t)D * E * 2);      // 4 MB
    u16*   w1T  = (u16*)alloc((size_t)F * D * 2);      // 8 MB
    u16*   w2T  = (u16*)alloc((size_t)D * F * 2);      // 8 MB
    float* bcat = (float*)alloc((size_t)E3 * 4);
    u16*   xn   = (u16*)alloc((size_t)BN * D * 2);     // 8 MB (reused as xn2)
    u16*   QKV  = (u16*)alloc((size_t)BN * E3 * 2);    // 48 MB (reused: P, h)
    u16*   Vt   = (u16*)alloc((size_t)Bb * E * N * 2); // 16 MB (reused as x2 fp32)
    u16*   Amat = (u16*)alloc((size_t)Bb * N * N * 2); // 32 MB (reused as parts)
    float* den  = (float*)alloc((size_t)BN * 4);

    u16*   xn2 = xn;
    u16*   P   = QKV;                  // [BN,E] bf16
    u16*   h   = QKV + (size_t)8 * 1024 * 1024;  // [BN,F] bf16
    float* x2  = (float*)Vt;           // [BN,D] fp32
    float* pt0 = (float*)Amat;         // split-K partial 0
    float* pt1 = pt0 + (size_t)BN * D; // split-K partial 1

    dim3 blk(256);

    // ---- prep: biases + den zero ----
    prep<<<dim3((BN + 255) / 256), blk, 0, stream>>>(q_b, k_b, v_b, bcat, den, E, BN);

    // ---- weight transposes ----
    transpose_qkv<<<dim3(E / 32, D / 32, 3), blk, 0, stream>>>(q_w, k_w, v_w, qkvT, D, E);
    transpose_bf16<float><<<dim3(D / 32, E / 32, 1), blk, 0, stream>>>(o_w, oT, E, D, D, 0, 0);
    transpose_bf16<float><<<dim3(F / 32, D / 32, 1), blk, 0, stream>>>(w1, w1T, D, F, F, 0, 0);
    transpose_bf16<float><<<dim3(D / 32, F / 32, 1), blk, 0, stream>>>(w2, w2T, F, D, D, 0, 0);

    // ---- LN1 ----
    ln_bf16<<<BN, blk, 0, stream>>>(x, ln1g, ln1b, xn, D);

    // ---- fused QKV projection: [BN,3E], elu+1 on Q,K cols (K=1024 -> BK=32) ----
    gemm_nt<EPI_QKV, 32><<<dim3(E3 / 128, BN / 128, 1), blk, 0, stream>>>(
        xn, qkvT, QKV, bcat, nullptr, BN, E3, D, D, D, 0, 0, 0, 0);

    // ---- V^T per batch: [N,E] (stride 3E) -> [E,N] ----
    transpose_bf16<u16><<<dim3(E / 32, N / 32, Bb), blk, 0, stream>>>(
        QKV + 2 * E, Vt, N, E, E3, (ll)N * E3, (ll)E * N);

    // ---- A = tril(Q K^T) per batch, fused rowsum -> den (K=2048 -> BK=64) ----
    gemm_nt<EPI_TRIL, 64><<<dim3(N / 128, N / 128, Bb), blk, 0, stream>>>(
        QKV, QKV + E, Amat, nullptr, den, N, N, E, E3, E3,
        (ll)N * E3, (ll)N * E3, (ll)N * N, (ll)N);

    // ---- P = (A @ V) / den (triangular K-loop, BK=64) ----
    gemm_nt<EPI_DIV, 64><<<dim3(E / 128, N / 128, Bb), blk, 0, stream>>>(
        Amat, Vt, P, nullptr, den, N, E, N, N, N,
        (ll)N * N, (ll)E * N, (ll)N * E, (ll)N);

    // ---- split-K=2: parts = P @ o_w (fp32), K=1024/split -> BK=32 ----
    gemm_nt<EPI_PART, 32><<<dim3(D / 128, BN / 128, 2), blk, 0, stream>>>(
        P, oT, pt0, nullptr, nullptr, BN, D, E / 2, E, E,
        (ll)(E / 2), (ll)(E / 2), (ll)BN * D, 0);

    // ---- x2 = x + p0 + p1 + o_b ; xn2 = LN2(x2) ----
    combine_ln<<<BN, blk, 0, stream>>>(x, pt0, pt1, o_b, ln2g, ln2b, x2, xn2);

    // ---- h = gelu(xn2 @ w1 + b1) (K=1024 -> BK=32) ----
    gemm_nt<EPI_GELU, 32><<<dim3(F / 128, BN / 128, 1), blk, 0, stream>>>(
        xn2, w1T, h, b1, nullptr, BN, F, D, D, D, 0, 0, 0, 0);

    // ---- split-K=2: parts = h @ w2 (fp32), K=2048/split -> BK=64 ----
    gemm_nt<EPI_PART, 64><<<dim3(D / 128, BN / 128, 2), blk, 0, stream>>>(
        h, w2T, pt0, nullptr, nullptr, BN, D, F / 2, F, F,
        (ll)(F / 2), (ll)(F / 2), (ll)BN * D, 0);

    // ---- out = x2 + p0 + p1 + b2 ----
    combine_out<<<dim3(BN * D / 4 / 256), blk, 0, stream>>>(x2, pt0, pt1, b2, out);
}

// Round 8
// 470.774 us; speedup vs baseline: 1.1105x; 1.0317x over previous
//
#include <hip/hip_runtime.h>
#include <math.h>

typedef unsigned short u16;
typedef short s16x8 __attribute__((ext_vector_type(8)));
typedef float f32x4 __attribute__((ext_vector_type(4)));
typedef long long ll;

__device__ inline u16 f2bf(float f) {
    unsigned u = __float_as_uint(f);
    u += 0x7fffu + ((u >> 16) & 1u);
    return (u16)(u >> 16);
}
__device__ inline float bf2f(u16 h) { return __uint_as_float(((unsigned)h) << 16); }

// async global->LDS, 16B per lane; LDS dest = wave-uniform base + lane*16
__device__ __forceinline__ void glds16(const u16* g, u16* l) {
    __builtin_amdgcn_global_load_lds(
        (__attribute__((address_space(1))) void*)(void*)g,
        (__attribute__((address_space(3))) void*)l, 16, 0, 0);
}

// ---------------- LayerNorm -> bf16 (one block per row, D=1024) ----------------
__global__ __launch_bounds__(256) void ln_bf16(const float* __restrict__ x,
                                               const float* __restrict__ g,
                                               const float* __restrict__ b,
                                               u16* __restrict__ out, int D) {
    int row = blockIdx.x;
    const float* xr = x + (size_t)row * D;
    int t = threadIdx.x;
    float4 v = ((const float4*)xr)[t];
    float s = v.x + v.y + v.z + v.w;
    __shared__ float sm[4];
    #pragma unroll
    for (int o = 32; o > 0; o >>= 1) s += __shfl_down(s, o, 64);
    int lane = t & 63, wv = t >> 6;
    if (lane == 0) sm[wv] = s;
    __syncthreads();
    float mean = (sm[0] + sm[1] + sm[2] + sm[3]) * (1.0f / 1024.0f);
    float dx = v.x - mean, dy = v.y - mean, dz = v.z - mean, dw = v.w - mean;
    float s2 = dx * dx + dy * dy + dz * dz + dw * dw;
    __syncthreads();
    #pragma unroll
    for (int o = 32; o > 0; o >>= 1) s2 += __shfl_down(s2, o, 64);
    if (lane == 0) sm[wv] = s2;
    __syncthreads();
    float var = (sm[0] + sm[1] + sm[2] + sm[3]) * (1.0f / 1024.0f);
    float rstd = rsqrtf(var + 1e-5f);
    float4 gg = ((const float4*)g)[t], bb = ((const float4*)b)[t];
    ushort4 o4;
    o4.x = f2bf(dx * rstd * gg.x + bb.x);
    o4.y = f2bf(dy * rstd * gg.y + bb.y);
    o4.z = f2bf(dz * rstd * gg.z + bb.z);
    o4.w = f2bf(dw * rstd * gg.w + bb.w);
    ((ushort4*)(out + (size_t)row * D))[t] = o4;
}

// ---------------- combine split-K parts + residual + bias, then LayerNorm ----------------
__global__ __launch_bounds__(256) void combine_ln(
    const float* __restrict__ x, const float* __restrict__ p0,
    const float* __restrict__ p1, const float* __restrict__ ob,
    const float* __restrict__ g, const float* __restrict__ b,
    float* __restrict__ x2, u16* __restrict__ xn2) {
    int row = blockIdx.x;
    int t = threadIdx.x;
    size_t base = (size_t)row * 256;  // float4 units
    float4 v = ((const float4*)x)[base + t];
    float4 a0 = ((const float4*)p0)[base + t];
    float4 a1 = ((const float4*)p1)[base + t];
    float4 ob4 = ((const float4*)ob)[t];
    v.x += a0.x + a1.x + ob4.x;
    v.y += a0.y + a1.y + ob4.y;
    v.z += a0.z + a1.z + ob4.z;
    v.w += a0.w + a1.w + ob4.w;
    ((float4*)x2)[base + t] = v;
    float s = v.x + v.y + v.z + v.w;
    __shared__ float sm[4];
    #pragma unroll
    for (int o = 32; o > 0; o >>= 1) s += __shfl_down(s, o, 64);
    int lane = t & 63, wv = t >> 6;
    if (lane == 0) sm[wv] = s;
    __syncthreads();
    float mean = (sm[0] + sm[1] + sm[2] + sm[3]) * (1.0f / 1024.0f);
    float dx = v.x - mean, dy = v.y - mean, dz = v.z - mean, dw = v.w - mean;
    float s2 = dx * dx + dy * dy + dz * dz + dw * dw;
    __syncthreads();
    #pragma unroll
    for (int o = 32; o > 0; o >>= 1) s2 += __shfl_down(s2, o, 64);
    if (lane == 0) sm[wv] = s2;
    __syncthreads();
    float var = (sm[0] + sm[1] + sm[2] + sm[3]) * (1.0f / 1024.0f);
    float rstd = rsqrtf(var + 1e-5f);
    float4 gg = ((const float4*)g)[t], bb = ((const float4*)b)[t];
    ushort4 o4;
    o4.x = f2bf(dx * rstd * gg.x + bb.x);
    o4.y = f2bf(dy * rstd * gg.y + bb.y);
    o4.z = f2bf(dz * rstd * gg.z + bb.z);
    o4.w = f2bf(dw * rstd * gg.w + bb.w);
    ((ushort4*)(xn2 + (size_t)row * 1024))[t] = o4;
}

// out = x2 + p0 + p1 + b2
__global__ __launch_bounds__(256) void combine_out(
    const float* __restrict__ x2, const float* __restrict__ p0,
    const float* __restrict__ p1, const float* __restrict__ b2,
    float* __restrict__ out) {
    size_t i = (size_t)blockIdx.x * 256 + threadIdx.x;
    int col4 = (int)(i & 255);
    float4 v = ((const float4*)x2)[i];
    float4 a0 = ((const float4*)p0)[i];
    float4 a1 = ((const float4*)p1)[i];
    float4 bb = ((const float4*)b2)[col4];
    v.x += a0.x + a1.x + bb.x;
    v.y += a0.y + a1.y + bb.y;
    v.z += a0.z + a1.z + bb.z;
    v.w += a0.w + a1.w + bb.w;
    ((float4*)out)[i] = v;
}

// ---------------- prep: pack q_b,k_b,v_b -> bcat[3E]; zero den[BN] ----------------
__global__ void prep(const float* __restrict__ qb, const float* __restrict__ kb,
                     const float* __restrict__ vb, float* __restrict__ bcat,
                     float* __restrict__ den, int E, int BN) {
    int i = blockIdx.x * 256 + threadIdx.x;
    if (i < E) {
        bcat[i] = qb[i];
        bcat[E + i] = kb[i];
        bcat[2 * E + i] = vb[i];
    }
    if (i < BN) den[i] = 0.f;
}

// ---------------- all 6 weight transposes in one dispatch ----------------
// each src is [R,C] fp32 -> dst [C,R] bf16. grid (4096, 6); z with fewer
// tiles early-return (q/k/v/o_w have 2048 tiles; w1/w2 have 4096).
__global__ __launch_bounds__(256) void transpose_all(
    const float* __restrict__ q_w, const float* __restrict__ k_w,
    const float* __restrict__ v_w, const float* __restrict__ o_w,
    const float* __restrict__ w1, const float* __restrict__ w2,
    u16* __restrict__ qkvT, u16* __restrict__ oT,
    u16* __restrict__ w1T, u16* __restrict__ w2T) {
    int z = blockIdx.y;
    const float* src;
    u16* dst;
    int R, C, tprLog;  // tiles-per-row = C/32, log2
    switch (z) {
        case 0: src = q_w; dst = qkvT;                           R = 1024; C = 2048; tprLog = 6; break;
        case 1: src = k_w; dst = qkvT + (size_t)2 * 1024 * 1024; R = 1024; C = 2048; tprLog = 6; break;
        case 2: src = v_w; dst = qkvT + (size_t)4 * 1024 * 1024; R = 1024; C = 2048; tprLog = 6; break;
        case 3: src = o_w; dst = oT;                             R = 2048; C = 1024; tprLog = 5; break;
        case 4: src = w1;  dst = w1T;                            R = 1024; C = 4096; tprLog = 7; break;
        default: src = w2; dst = w2T;                            R = 4096; C = 1024; tprLog = 5; break;
    }
    int bx = blockIdx.x;
    int ntiles = (R >> 5) << (tprLog);  // (R/32)*(C/32)
    if (bx >= ntiles) return;
    int c0 = (bx & ((1 << tprLog) - 1)) * 32;
    int r0 = (bx >> tprLog) * 32;
    __shared__ u16 tile[32][33];
    int tx = threadIdx.x & 31, ty = threadIdx.x >> 5;
    #pragma unroll
    for (int i = 0; i < 32; i += 8)
        tile[ty + i][tx] = f2bf(src[(size_t)(r0 + ty + i) * C + c0 + tx]);
    __syncthreads();
    #pragma unroll
    for (int i = 0; i < 32; i += 8)
        dst[(size_t)(c0 + ty + i) * R + r0 + tx] = tile[tx][ty + i];
}

// generic bf16 transpose (used for V^T): in [R,C] (row stride ldIn) -> out [C,R]
__global__ __launch_bounds__(256) void transpose_u16(const u16* __restrict__ in,
                                                     u16* __restrict__ out,
                                                     int R, int C, int ldIn,
                                                     ll sIn, ll sOut) {
    in += (size_t)blockIdx.z * sIn;
    out += (size_t)blockIdx.z * sOut;
    __shared__ u16 tile[32][33];
    int tx = threadIdx.x & 31, ty = threadIdx.x >> 5;
    int c0 = blockIdx.x * 32, r0 = blockIdx.y * 32;
    #pragma unroll
    for (int i = 0; i < 32; i += 8)
        tile[ty + i][tx] = in[(size_t)(r0 + ty + i) * ldIn + c0 + tx];
    __syncthreads();
    #pragma unroll
    for (int i = 0; i < 32; i += 8)
        out[(size_t)(c0 + ty + i) * R + r0 + tx] = tile[tx][ty + i];
}

// ---------------- GEMM NT: C[m,n] = sum_k A[m,k]*B[n,k] ----------------
// 256 threads, 128x128 tile; BKt = 32 or 64; staging via global_load_lds.
// LDS XOR-swizzled at 16B-chunk granularity:
//   BKt=32 (4 chunks/row): chunk(r,q) = r*4 + ((q + (r>>1)) & 3)
//   BKt=64 (8 chunks/row): chunk(r,q) = r*8 + ((q + (r&7)) & 7)
// Both give 2 lanes/bank-group on every ds_read_b128 (free) and keep the
// global_load_lds "base + lane*16" write contiguous.
enum { EPI_QKV = 0, EPI_TRIL = 2, EPI_DIV = 3, EPI_GELU = 5, EPI_PART = 6 };

#define TM 128
#define TN 128

template <int EPI, int BKt>
__global__ __launch_bounds__(256) void gemm_nt(
    const u16* __restrict__ A, const u16* __restrict__ B, void* __restrict__ Cv,
    const float* __restrict__ bias, float* __restrict__ den,
    int M, int N, int K, int lda, int ldb,
    ll sA, ll sB, ll sC, ll sAux) {
    int z = blockIdx.z;
    A += (size_t)z * sA;
    B += (size_t)z * sB;

    // panel-of-4 swizzle (gridDim.y % 4 == 0 for all our launches)
    int nb = gridDim.x;
    int bl = blockIdx.y * nb + blockIdx.x;
    int panel = nb * 4;
    int pp = bl / panel, rr = bl - pp * panel;
    int m0 = (pp * 4 + (rr & 3)) * TM;
    int n0 = (rr >> 2) * TN;

    int t = threadIdx.x;

    // strictly-above-diagonal tril blocks: write zeros (keeps Amat fully
    // defined in-call; the region aliases split-K partials of prior replays)
    if (EPI == EPI_TRIL && n0 > m0 + (TM - 1)) {
        u16* C = (u16*)Cv + (size_t)z * sC;
        #pragma unroll
        for (int s = 0; s < 8; ++s) {
            int v = t + 256 * s;          // 0..2047
            int row = v >> 4, cf = (v & 15) * 8;
            *(uint4*)&C[(size_t)(m0 + row) * N + n0 + cf] = make_uint4(0, 0, 0, 0);
        }
        return;
    }

    __shared__ __align__(16) u16 As[TM * BKt];
    __shared__ __align__(16) u16 Bs[TN * BKt];

    f32x4 acc[4][4];
    #pragma unroll
    for (int i = 0; i < 4; i++)
        #pragma unroll
        for (int j = 0; j < 4; j++) { f32x4 zz = {0.f, 0.f, 0.f, 0.f}; acc[i][j] = zz; }

    int kend = (EPI == EPI_DIV) ? (m0 + TM < K ? m0 + TM : K) : K;

    int lane = t & 63, wv = t >> 6;
    int lr = lane & 15, q = lane >> 4;
    int wm = (wv & 1) * 64, wn = (wv >> 1) * 64;

    u16* lA = As + wv * 32 * BKt;  // wave-uniform LDS base (32 rows per wave)
    u16* lB = Bs + wv * 32 * BKt;

    // ---- staging addresses (swizzle-aware) ----
    int srow, skf;
    if (BKt == 32) {
        srow = wv * 32 + (lane >> 2);
        skf = (((lane & 3) - ((lane >> 3) & 3)) & 3) * 8;
    } else {
        srow = wv * 32 + (lane >> 3);
        skf = (((lane & 7) - (lane >> 3)) & 7) * 8;
    }
    const u16* gA0 = A + (size_t)(m0 + srow) * lda + skf;
    const u16* gB0 = B + (size_t)(n0 + srow) * ldb + skf;

    // ---- fragment read offsets (u16 units) ----
    int ca[2][4], cb[2][4];
    #pragma unroll
    for (int i = 0; i < 4; i++) {
        int ra = wm + i * 16 + lr;
        int rb = wn + i * 16 + lr;
        if (BKt == 32) {
            ca[0][i] = (ra * 4 + ((q + (ra >> 1)) & 3)) * 8;
            cb[0][i] = (rb * 4 + ((q + (rb >> 1)) & 3)) * 8;
        } else {
            ca[0][i] = (ra * 8 + ((q + (ra & 7)) & 7)) * 8;
            ca[1][i] = (ra * 8 + ((4 + q + (ra & 7)) & 7)) * 8;
            cb[0][i] = (rb * 8 + ((q + (rb & 7)) & 7)) * 8;
            cb[1][i] = (rb * 8 + ((4 + q + (rb & 7)) & 7)) * 8;
        }
    }

    for (int k0 = 0; k0 < kend; k0 += BKt) {
        if (BKt == 32) {
            glds16(gA0 + k0, lA);
            glds16(gA0 + k0 + (size_t)16 * lda, lA + 16 * BKt);
            glds16(gB0 + k0, lB);
            glds16(gB0 + k0 + (size_t)16 * ldb, lB + 16 * BKt);
        } else {
            #pragma unroll
            for (int r = 0; r < 4; ++r) {
                glds16(gA0 + k0 + (size_t)(8 * r) * lda, lA + r * 8 * BKt);
                glds16(gB0 + k0 + (size_t)(8 * r) * ldb, lB + r * 8 * BKt);
            }
        }
        __syncthreads();  // drains vmcnt -> LDS tiles ready
        #pragma unroll
        for (int kk = 0; kk < BKt / 32; ++kk) {
            s16x8 af[4], bfr[4];
            #pragma unroll
            for (int i = 0; i < 4; i++) af[i] = *(const s16x8*)&As[ca[kk][i]];
            #pragma unroll
            for (int j = 0; j < 4; j++) bfr[j] = *(const s16x8*)&Bs[cb[kk][j]];
            #pragma unroll
            for (int i = 0; i < 4; i++)
                #pragma unroll
                for (int j = 0; j < 4; j++)
                    acc[i][j] = __builtin_amdgcn_mfma_f32_16x16x32_bf16(af[i], bfr[j], acc[i][j], 0, 0, 0);
        }
        __syncthreads();  // protect LDS from next iteration's overwrite
    }

    u16* Cb = (u16*)Cv + (size_t)z * sC;
    float* Cf = (float*)Cv + (size_t)z * sC;
    bool isQK = (EPI == EPI_QKV) && (n0 < 4096);  // block-uniform
    #pragma unroll
    for (int i = 0; i < 4; i++) {
        #pragma unroll
        for (int r = 0; r < 4; r++) {
            int row = m0 + wm + i * 16 + q * 4 + r;
            float rs = 0.f;
            #pragma unroll
            for (int j = 0; j < 4; j++) {
                int col = n0 + wn + j * 16 + lr;
                float v = acc[i][j][r];
                if (EPI == EPI_QKV) {
                    v += bias[col];
                    if (isQK) v = (v > 0.f) ? (v + 1.f) : __expf(v);  // elu+1
                    Cb[(size_t)row * N + col] = f2bf(v);
                } else if (EPI == EPI_TRIL) {
                    v = (col <= row) ? v : 0.f;
                    rs += v;
                    Cb[(size_t)row * N + col] = f2bf(v);
                } else if (EPI == EPI_DIV) {
                    float d = den[(size_t)z * sAux + row] + 1e-6f;
                    Cb[(size_t)row * N + col] = f2bf(v / d);
                } else if (EPI == EPI_GELU) {
                    v += bias[col];
                    // gelu(v) ~ v * sigmoid(2u), u = 0.79788456*(v + 0.044715 v^3)
                    float u = v * (0.7978845608f + 0.0356774081f * v * v);
                    u = fminf(u, 40.f);
                    float e = __expf(2.f * u);
                    v = v * __fdividef(e, e + 1.f);
                    Cb[(size_t)row * N + col] = f2bf(v);
                } else if (EPI == EPI_PART) {
                    Cf[(size_t)row * N + col] = v;
                }
            }
            if (EPI == EPI_TRIL) {
                // reduce rs over the 16 lanes (lr) of this q-group -> row sum of 64 cols
                #pragma unroll
                for (int m = 1; m < 16; m <<= 1) rs += __shfl_xor(rs, m, 16);
                if (lr == 0) atomicAdd(&den[(size_t)z * sAux + row], rs);
            }
        }
    }
}

extern "C" void kernel_launch(void* const* d_in, const int* in_sizes, int n_in,
                              void* d_out, int out_size, void* d_ws, size_t ws_size,
                              hipStream_t stream) {
    const float* x    = (const float*)d_in[0];
    const float* q_w  = (const float*)d_in[1];
    const float* q_b  = (const float*)d_in[2];
    const float* k_w  = (const float*)d_in[3];
    const float* k_b  = (const float*)d_in[4];
    const float* v_w  = (const float*)d_in[5];
    const float* v_b  = (const float*)d_in[6];
    const float* o_w  = (const float*)d_in[7];
    const float* o_b  = (const float*)d_in[8];
    const float* ln1g = (const float*)d_in[9];
    const float* ln1b = (const float*)d_in[10];
    const float* ln2g = (const float*)d_in[11];
    const float* ln2b = (const float*)d_in[12];
    const float* w1   = (const float*)d_in[13];
    const float* b1   = (const float*)d_in[14];
    const float* w2   = (const float*)d_in[15];
    const float* b2   = (const float*)d_in[16];
    float* out = (float*)d_out;

    constexpr int Bb = 2, N = 2048, D = 1024, E = 2048, F = 4096;
    constexpr int BN = Bb * N;     // 4096
    constexpr int E3 = 3 * E;      // 6144

    char* ws = (char*)d_ws;
    size_t off = 0;
    auto alloc = [&](size_t bytes) -> void* {
        void* p = ws + off;
        off += (bytes + 255) & ~(size_t)255;
        return p;
    };
    u16*   qkvT = (u16*)alloc((size_t)E3 * D * 2);     // 12 MB
    u16*   oT   = (u16*)alloc((size_t)D * E * 2);      // 4 MB
    u16*   w1T  = (u16*)alloc((size_t)F * D * 2);      // 8 MB
    u16*   w2T  = (u16*)alloc((size_t)D * F * 2);      // 8 MB
    float* bcat = (float*)alloc((size_t)E3 * 4);
    u16*   xn   = (u16*)alloc((size_t)BN * D * 2);     // 8 MB (reused as xn2)
    u16*   QKV  = (u16*)alloc((size_t)BN * E3 * 2);    // 48 MB (reused: P, h)
    u16*   Vt   = (u16*)alloc((size_t)Bb * E * N * 2); // 16 MB (reused as x2 fp32)
    u16*   Amat = (u16*)alloc((size_t)Bb * N * N * 2); // 32 MB (reused as parts)
    float* den  = (float*)alloc((size_t)BN * 4);

    u16*   xn2 = xn;
    u16*   P   = QKV;                  // [BN,E] bf16
    u16*   h   = QKV + (size_t)8 * 1024 * 1024;  // [BN,F] bf16
    float* x2  = (float*)Vt;           // [BN,D] fp32
    float* pt0 = (float*)Amat;         // split-K partial 0
    float* pt1 = pt0 + (size_t)BN * D; // split-K partial 1

    dim3 blk(256);

    // ---- prep: biases + den zero ----
    prep<<<dim3((BN + 255) / 256), blk, 0, stream>>>(q_b, k_b, v_b, bcat, den, E, BN);

    // ---- all weight transposes, one dispatch ----
    transpose_all<<<dim3(4096, 6), blk, 0, stream>>>(
        q_w, k_w, v_w, o_w, w1, w2, qkvT, oT, w1T, w2T);

    // ---- LN1 ----
    ln_bf16<<<BN, blk, 0, stream>>>(x, ln1g, ln1b, xn, D);

    // ---- fused QKV projection: [BN,3E], elu+1 on Q,K cols (BK=64) ----
    gemm_nt<EPI_QKV, 64><<<dim3(E3 / 128, BN / 128, 1), blk, 0, stream>>>(
        xn, qkvT, QKV, bcat, nullptr, BN, E3, D, D, D, 0, 0, 0, 0);

    // ---- V^T per batch: [N,E] (stride 3E) -> [E,N] ----
    transpose_u16<<<dim3(E / 32, N / 32, Bb), blk, 0, stream>>>(
        QKV + 2 * E, Vt, N, E, E3, (ll)N * E3, (ll)E * N);

    // ---- A = tril(Q K^T) per batch, fused rowsum -> den (BK=64) ----
    gemm_nt<EPI_TRIL, 64><<<dim3(N / 128, N / 128, Bb), blk, 0, stream>>>(
        QKV, QKV + E, Amat, nullptr, den, N, N, E, E3, E3,
        (ll)N * E3, (ll)N * E3, (ll)N * N, (ll)N);

    // ---- P = (A @ V) / den (triangular K-loop, BK=64) ----
    gemm_nt<EPI_DIV, 64><<<dim3(E / 128, N / 128, Bb), blk, 0, stream>>>(
        Amat, Vt, P, nullptr, den, N, E, N, N, N,
        (ll)N * N, (ll)E * N, (ll)N * E, (ll)N);

    // ---- split-K=2: parts = P @ o_w (fp32), BK=64 ----
    gemm_nt<EPI_PART, 64><<<dim3(D / 128, BN / 128, 2), blk, 0, stream>>>(
        P, oT, pt0, nullptr, nullptr, BN, D, E / 2, E, E,
        (ll)(E / 2), (ll)(E / 2), (ll)BN * D, 0);

    // ---- x2 = x + p0 + p1 + o_b ; xn2 = LN2(x2) ----
    combine_ln<<<BN, blk, 0, stream>>>(x, pt0, pt1, o_b, ln2g, ln2b, x2, xn2);

    // ---- h = gelu(xn2 @ w1 + b1) (BK=64) ----
    gemm_nt<EPI_GELU, 64><<<dim3(F / 128, BN / 128, 1), blk, 0, stream>>>(
        xn2, w1T, h, b1, nullptr, BN, F, D, D, D, 0, 0, 0, 0);

    // ---- split-K=2: parts = h @ w2 (fp32), BK=64 ----
    gemm_nt<EPI_PART, 64><<<dim3(D / 128, BN / 128, 2), blk, 0, stream>>>(
        h, w2T, pt0, nullptr, nullptr, BN, D, F / 2, F, F,
        (ll)(F / 2), (ll)(F / 2), (ll)BN * D, 0);

    // ---- out = x2 + p0 + p1 + b2 ----
    combine_out<<<dim3(BN * D / 4 / 256), blk, 0, stream>>>(x2, pt0, pt1, b2, out);
}

// Round 9
// 463.775 us; speedup vs baseline: 1.1273x; 1.0151x over previous
//
#include <hip/hip_runtime.h>
#include <math.h>

typedef unsigned short u16;
typedef short s16x8 __attribute__((ext_vector_type(8)));
typedef float f32x4 __attribute__((ext_vector_type(4)));
typedef long long ll;

__device__ inline u16 f2bf(float f) {
    unsigned u = __float_as_uint(f);
    u += 0x7fffu + ((u >> 16) & 1u);
    return (u16)(u >> 16);
}
__device__ inline float bf2f(u16 h) { return __uint_as_float(((unsigned)h) << 16); }

// async global->LDS, 16B per lane; LDS dest = wave-uniform base + lane*16
__device__ __forceinline__ void glds16(const u16* g, u16* l) {
    __builtin_amdgcn_global_load_lds(
        (__attribute__((address_space(1))) void*)(void*)g,
        (__attribute__((address_space(3))) void*)l, 16, 0, 0);
}

// ---------------- LayerNorm -> bf16 (one block per row, D=1024) ----------------
__global__ __launch_bounds__(256) void ln_bf16(const float* __restrict__ x,
                                               const float* __restrict__ g,
                                               const float* __restrict__ b,
                                               u16* __restrict__ out, int D) {
    int row = blockIdx.x;
    const float* xr = x + (size_t)row * D;
    int t = threadIdx.x;
    float4 v = ((const float4*)xr)[t];
    float s = v.x + v.y + v.z + v.w;
    __shared__ float sm[4];
    #pragma unroll
    for (int o = 32; o > 0; o >>= 1) s += __shfl_down(s, o, 64);
    int lane = t & 63, wv = t >> 6;
    if (lane == 0) sm[wv] = s;
    __syncthreads();
    float mean = (sm[0] + sm[1] + sm[2] + sm[3]) * (1.0f / 1024.0f);
    float dx = v.x - mean, dy = v.y - mean, dz = v.z - mean, dw = v.w - mean;
    float s2 = dx * dx + dy * dy + dz * dz + dw * dw;
    __syncthreads();
    #pragma unroll
    for (int o = 32; o > 0; o >>= 1) s2 += __shfl_down(s2, o, 64);
    if (lane == 0) sm[wv] = s2;
    __syncthreads();
    float var = (sm[0] + sm[1] + sm[2] + sm[3]) * (1.0f / 1024.0f);
    float rstd = rsqrtf(var + 1e-5f);
    float4 gg = ((const float4*)g)[t], bb = ((const float4*)b)[t];
    ushort4 o4;
    o4.x = f2bf(dx * rstd * gg.x + bb.x);
    o4.y = f2bf(dy * rstd * gg.y + bb.y);
    o4.z = f2bf(dz * rstd * gg.z + bb.z);
    o4.w = f2bf(dw * rstd * gg.w + bb.w);
    ((ushort4*)(out + (size_t)row * D))[t] = o4;
}

// ---------------- combine split-K parts + residual + bias, then LayerNorm ----------------
__global__ __launch_bounds__(256) void combine_ln(
    const float* __restrict__ x, const float* __restrict__ p0,
    const float* __restrict__ p1, const float* __restrict__ ob,
    const float* __restrict__ g, const float* __restrict__ b,
    float* __restrict__ x2, u16* __restrict__ xn2) {
    int row = blockIdx.x;
    int t = threadIdx.x;
    size_t base = (size_t)row * 256;  // float4 units
    float4 v = ((const float4*)x)[base + t];
    float4 a0 = ((const float4*)p0)[base + t];
    float4 a1 = ((const float4*)p1)[base + t];
    float4 ob4 = ((const float4*)ob)[t];
    v.x += a0.x + a1.x + ob4.x;
    v.y += a0.y + a1.y + ob4.y;
    v.z += a0.z + a1.z + ob4.z;
    v.w += a0.w + a1.w + ob4.w;
    ((float4*)x2)[base + t] = v;
    float s = v.x + v.y + v.z + v.w;
    __shared__ float sm[4];
    #pragma unroll
    for (int o = 32; o > 0; o >>= 1) s += __shfl_down(s, o, 64);
    int lane = t & 63, wv = t >> 6;
    if (lane == 0) sm[wv] = s;
    __syncthreads();
    float mean = (sm[0] + sm[1] + sm[2] + sm[3]) * (1.0f / 1024.0f);
    float dx = v.x - mean, dy = v.y - mean, dz = v.z - mean, dw = v.w - mean;
    float s2 = dx * dx + dy * dy + dz * dz + dw * dw;
    __syncthreads();
    #pragma unroll
    for (int o = 32; o > 0; o >>= 1) s2 += __shfl_down(s2, o, 64);
    if (lane == 0) sm[wv] = s2;
    __syncthreads();
    float var = (sm[0] + sm[1] + sm[2] + sm[3]) * (1.0f / 1024.0f);
    float rstd = rsqrtf(var + 1e-5f);
    float4 gg = ((const float4*)g)[t], bb = ((const float4*)b)[t];
    ushort4 o4;
    o4.x = f2bf(dx * rstd * gg.x + bb.x);
    o4.y = f2bf(dy * rstd * gg.y + bb.y);
    o4.z = f2bf(dz * rstd * gg.z + bb.z);
    o4.w = f2bf(dw * rstd * gg.w + bb.w);
    ((ushort4*)(xn2 + (size_t)row * 1024))[t] = o4;
}

// out = x2 + p0 + p1 + b2
__global__ __launch_bounds__(256) void combine_out(
    const float* __restrict__ x2, const float* __restrict__ p0,
    const float* __restrict__ p1, const float* __restrict__ b2,
    float* __restrict__ out) {
    size_t i = (size_t)blockIdx.x * 256 + threadIdx.x;
    int col4 = (int)(i & 255);
    float4 v = ((const float4*)x2)[i];
    float4 a0 = ((const float4*)p0)[i];
    float4 a1 = ((const float4*)p1)[i];
    float4 bb = ((const float4*)b2)[col4];
    v.x += a0.x + a1.x + bb.x;
    v.y += a0.y + a1.y + bb.y;
    v.z += a0.z + a1.z + bb.z;
    v.w += a0.w + a1.w + bb.w;
    ((float4*)out)[i] = v;
}

// ---------------- prep: pack q_b,k_b,v_b -> bcat[3E]; zero den[BN] ----------------
__global__ void prep(const float* __restrict__ qb, const float* __restrict__ kb,
                     const float* __restrict__ vb, float* __restrict__ bcat,
                     float* __restrict__ den, int E, int BN) {
    int i = blockIdx.x * 256 + threadIdx.x;
    if (i < E) {
        bcat[i] = qb[i];
        bcat[E + i] = kb[i];
        bcat[2 * E + i] = vb[i];
    }
    if (i < BN) den[i] = 0.f;
}

// ---------------- all 6 weight transposes in one dispatch ----------------
// each src is [R,C] fp32 -> dst [C,R] bf16. grid (4096, 6); z with fewer
// tiles early-return (q/k/v/o_w have 2048 tiles; w1/w2 have 4096).
__global__ __launch_bounds__(256) void transpose_all(
    const float* __restrict__ q_w, const float* __restrict__ k_w,
    const float* __restrict__ v_w, const float* __restrict__ o_w,
    const float* __restrict__ w1, const float* __restrict__ w2,
    u16* __restrict__ qkvT, u16* __restrict__ oT,
    u16* __restrict__ w1T, u16* __restrict__ w2T) {
    int z = blockIdx.y;
    const float* src;
    u16* dst;
    int R, C, tprLog;  // tiles-per-row = C/32, log2
    switch (z) {
        case 0: src = q_w; dst = qkvT;                           R = 1024; C = 2048; tprLog = 6; break;
        case 1: src = k_w; dst = qkvT + (size_t)2 * 1024 * 1024; R = 1024; C = 2048; tprLog = 6; break;
        case 2: src = v_w; dst = qkvT + (size_t)4 * 1024 * 1024; R = 1024; C = 2048; tprLog = 6; break;
        case 3: src = o_w; dst = oT;                             R = 2048; C = 1024; tprLog = 5; break;
        case 4: src = w1;  dst = w1T;                            R = 1024; C = 4096; tprLog = 7; break;
        default: src = w2; dst = w2T;                            R = 4096; C = 1024; tprLog = 5; break;
    }
    int bx = blockIdx.x;
    int ntiles = (R >> 5) << (tprLog);  // (R/32)*(C/32)
    if (bx >= ntiles) return;
    int c0 = (bx & ((1 << tprLog) - 1)) * 32;
    int r0 = (bx >> tprLog) * 32;
    __shared__ u16 tile[32][33];
    int tx = threadIdx.x & 31, ty = threadIdx.x >> 5;
    #pragma unroll
    for (int i = 0; i < 32; i += 8)
        tile[ty + i][tx] = f2bf(src[(size_t)(r0 + ty + i) * C + c0 + tx]);
    __syncthreads();
    #pragma unroll
    for (int i = 0; i < 32; i += 8)
        dst[(size_t)(c0 + ty + i) * R + r0 + tx] = tile[tx][ty + i];
}

// generic bf16 transpose (used for V^T): in [R,C] (row stride ldIn) -> out [C,R]
__global__ __launch_bounds__(256) void transpose_u16(const u16* __restrict__ in,
                                                     u16* __restrict__ out,
                                                     int R, int C, int ldIn,
                                                     ll sIn, ll sOut) {
    in += (size_t)blockIdx.z * sIn;
    out += (size_t)blockIdx.z * sOut;
    __shared__ u16 tile[32][33];
    int tx = threadIdx.x & 31, ty = threadIdx.x >> 5;
    int c0 = blockIdx.x * 32, r0 = blockIdx.y * 32;
    #pragma unroll
    for (int i = 0; i < 32; i += 8)
        tile[ty + i][tx] = in[(size_t)(r0 + ty + i) * ldIn + c0 + tx];
    __syncthreads();
    #pragma unroll
    for (int i = 0; i < 32; i += 8)
        out[(size_t)(c0 + ty + i) * R + r0 + tx] = tile[tx][ty + i];
}

// ---------------- GEMM NT: C[m,n] = sum_k A[m,k]*B[n,k] ----------------
// 256 threads, 128x128 tile; BKt = 32 or 64; staging via global_load_lds.
// LDS XOR-swizzled at 16B-chunk granularity (conflict-free, see R4-R8).
// Block->tile mapping:
//   TRIL/DIV: panel-of-4 (XCD round-robin mixes long/short kend blocks)
//   others:   per-XCD rectangle -- XCD g owns a (gy/2)x(gx/4) tile rect so
//             its private 4MB L2 keeps a compact A-panel + B-panel working
//             set (dispatch is round-robin over 8 XCDs by linear block id)
enum { EPI_QKV = 0, EPI_TRIL = 2, EPI_DIV = 3, EPI_GELU = 5, EPI_PART = 6 };

#define TM 128
#define TN 128

template <int EPI, int BKt>
__global__ __launch_bounds__(256) void gemm_nt(
    const u16* __restrict__ A, const u16* __restrict__ B, void* __restrict__ Cv,
    const float* __restrict__ bias, float* __restrict__ den,
    int M, int N, int K, int lda, int ldb,
    ll sA, ll sB, ll sC, ll sAux) {
    int z = blockIdx.z;
    A += (size_t)z * sA;
    B += (size_t)z * sB;

    int p = blockIdx.y * gridDim.x + blockIdx.x;
    int m0, n0;
    if (EPI == EPI_TRIL || EPI == EPI_DIV) {
        // panel-of-4 swizzle (proven; keeps kend load spread across XCDs)
        int nb = gridDim.x;
        int panel = nb * 4;
        int pp = p / panel, rr = p - pp * panel;
        m0 = (pp * 4 + (rr & 3)) * TM;
        n0 = (rr >> 2) * TN;
    } else {
        // per-XCD rectangular chunk (gx%4==0, gy%2==0 for all our launches)
        int g = p & 7, r = p >> 3;
        int lw = gridDim.x >> 2, lh = gridDim.y >> 1;
        int ly = r / lw, lx = r - ly * lw;
        m0 = ((g >> 2) * lh + ly) * TM;
        n0 = ((g & 3) * lw + lx) * TN;
    }

    int t = threadIdx.x;

    // strictly-above-diagonal tril blocks: write zeros (keeps Amat fully
    // defined in-call; the region aliases split-K partials of prior replays)
    if (EPI == EPI_TRIL && n0 > m0 + (TM - 1)) {
        u16* C = (u16*)Cv + (size_t)z * sC;
        #pragma unroll
        for (int s = 0; s < 8; ++s) {
            int v = t + 256 * s;          // 0..2047
            int row = v >> 4, cf = (v & 15) * 8;
            *(uint4*)&C[(size_t)(m0 + row) * N + n0 + cf] = make_uint4(0, 0, 0, 0);
        }
        return;
    }

    __shared__ __align__(16) u16 As[TM * BKt];
    __shared__ __align__(16) u16 Bs[TN * BKt];

    f32x4 acc[4][4];
    #pragma unroll
    for (int i = 0; i < 4; i++)
        #pragma unroll
        for (int j = 0; j < 4; j++) { f32x4 zz = {0.f, 0.f, 0.f, 0.f}; acc[i][j] = zz; }

    int kend = (EPI == EPI_DIV) ? (m0 + TM < K ? m0 + TM : K) : K;

    int lane = t & 63, wv = t >> 6;
    int lr = lane & 15, q = lane >> 4;
    int wm = (wv & 1) * 64, wn = (wv >> 1) * 64;

    u16* lA = As + wv * 32 * BKt;  // wave-uniform LDS base (32 rows per wave)
    u16* lB = Bs + wv * 32 * BKt;

    // ---- staging addresses (swizzle-aware) ----
    int srow, skf;
    if (BKt == 32) {
        srow = wv * 32 + (lane >> 2);
        skf = (((lane & 3) - ((lane >> 3) & 3)) & 3) * 8;
    } else {
        srow = wv * 32 + (lane >> 3);
        skf = (((lane & 7) - (lane >> 3)) & 7) * 8;
    }
    const u16* gA0 = A + (size_t)(m0 + srow) * lda + skf;
    const u16* gB0 = B + (size_t)(n0 + srow) * ldb + skf;

    // ---- fragment read offsets (u16 units) ----
    int ca[2][4], cb[2][4];
    #pragma unroll
    for (int i = 0; i < 4; i++) {
        int ra = wm + i * 16 + lr;
        int rb = wn + i * 16 + lr;
        if (BKt == 32) {
            ca[0][i] = (ra * 4 + ((q + (ra >> 1)) & 3)) * 8;
            cb[0][i] = (rb * 4 + ((q + (rb >> 1)) & 3)) * 8;
        } else {
            ca[0][i] = (ra * 8 + ((q + (ra & 7)) & 7)) * 8;
            ca[1][i] = (ra * 8 + ((4 + q + (ra & 7)) & 7)) * 8;
            cb[0][i] = (rb * 8 + ((q + (rb & 7)) & 7)) * 8;
            cb[1][i] = (rb * 8 + ((4 + q + (rb & 7)) & 7)) * 8;
        }
    }

    for (int k0 = 0; k0 < kend; k0 += BKt) {
        if (BKt == 32) {
            glds16(gA0 + k0, lA);
            glds16(gA0 + k0 + (size_t)16 * lda, lA + 16 * BKt);
            glds16(gB0 + k0, lB);
            glds16(gB0 + k0 + (size_t)16 * ldb, lB + 16 * BKt);
        } else {
            #pragma unroll
            for (int r = 0; r < 4; ++r) {
                glds16(gA0 + k0 + (size_t)(8 * r) * lda, lA + r * 8 * BKt);
                glds16(gB0 + k0 + (size_t)(8 * r) * ldb, lB + r * 8 * BKt);
            }
        }
        __syncthreads();  // drains vmcnt -> LDS tiles ready
        #pragma unroll
        for (int kk = 0; kk < BKt / 32; ++kk) {
            s16x8 af[4], bfr[4];
            #pragma unroll
            for (int i = 0; i < 4; i++) af[i] = *(const s16x8*)&As[ca[kk][i]];
            #pragma unroll
            for (int j = 0; j < 4; j++) bfr[j] = *(const s16x8*)&Bs[cb[kk][j]];
            #pragma unroll
            for (int i = 0; i < 4; i++)
                #pragma unroll
                for (int j = 0; j < 4; j++)
                    acc[i][j] = __builtin_amdgcn_mfma_f32_16x16x32_bf16(af[i], bfr[j], acc[i][j], 0, 0, 0);
        }
        __syncthreads();  // protect LDS from next iteration's overwrite
    }

    u16* Cb = (u16*)Cv + (size_t)z * sC;
    float* Cf = (float*)Cv + (size_t)z * sC;
    bool isQK = (EPI == EPI_QKV) && (n0 < 4096);  // block-uniform
    #pragma unroll
    for (int i = 0; i < 4; i++) {
        #pragma unroll
        for (int r = 0; r < 4; r++) {
            int row = m0 + wm + i * 16 + q * 4 + r;
            float rs = 0.f;
            #pragma unroll
            for (int j = 0; j < 4; j++) {
                int col = n0 + wn + j * 16 + lr;
                float v = acc[i][j][r];
                if (EPI == EPI_QKV) {
                    v += bias[col];
                    if (isQK) v = (v > 0.f) ? (v + 1.f) : __expf(v);  // elu+1
                    Cb[(size_t)row * N + col] = f2bf(v);
                } else if (EPI == EPI_TRIL) {
                    v = (col <= row) ? v : 0.f;
                    rs += v;
                    Cb[(size_t)row * N + col] = f2bf(v);
                } else if (EPI == EPI_DIV) {
                    float d = den[(size_t)z * sAux + row] + 1e-6f;
                    Cb[(size_t)row * N + col] = f2bf(v / d);
                } else if (EPI == EPI_GELU) {
                    v += bias[col];
                    // gelu(v) ~ v * sigmoid(2u), u = 0.79788456*(v + 0.044715 v^3)
                    float u = v * (0.7978845608f + 0.0356774081f * v * v);
                    u = fminf(u, 40.f);
                    float e = __expf(2.f * u);
                    v = v * __fdividef(e, e + 1.f);
                    Cb[(size_t)row * N + col] = f2bf(v);
                } else if (EPI == EPI_PART) {
                    Cf[(size_t)row * N + col] = v;
                }
            }
            if (EPI == EPI_TRIL) {
                // reduce rs over the 16 lanes (lr) of this q-group -> row sum of 64 cols
                #pragma unroll
                for (int m = 1; m < 16; m <<= 1) rs += __shfl_xor(rs, m, 16);
                if (lr == 0) atomicAdd(&den[(size_t)z * sAux + row], rs);
            }
        }
    }
}

extern "C" void kernel_launch(void* const* d_in, const int* in_sizes, int n_in,
                              void* d_out, int out_size, void* d_ws, size_t ws_size,
                              hipStream_t stream) {
    const float* x    = (const float*)d_in[0];
    const float* q_w  = (const float*)d_in[1];
    const float* q_b  = (const float*)d_in[2];
    const float* k_w  = (const float*)d_in[3];
    const float* k_b  = (const float*)d_in[4];
    const float* v_w  = (const float*)d_in[5];
    const float* v_b  = (const float*)d_in[6];
    const float* o_w  = (const float*)d_in[7];
    const float* o_b  = (const float*)d_in[8];
    const float* ln1g = (const float*)d_in[9];
    const float* ln1b = (const float*)d_in[10];
    const float* ln2g = (const float*)d_in[11];
    const float* ln2b = (const float*)d_in[12];
    const float* w1   = (const float*)d_in[13];
    const float* b1   = (const float*)d_in[14];
    const float* w2   = (const float*)d_in[15];
    const float* b2   = (const float*)d_in[16];
    float* out = (float*)d_out;

    constexpr int Bb = 2, N = 2048, D = 1024, E = 2048, F = 4096;
    constexpr int BN = Bb * N;     // 4096
    constexpr int E3 = 3 * E;      // 6144

    char* ws = (char*)d_ws;
    size_t off = 0;
    auto alloc = [&](size_t bytes) -> void* {
        void* p = ws + off;
        off += (bytes + 255) & ~(size_t)255;
        return p;
    };
    u16*   qkvT = (u16*)alloc((size_t)E3 * D * 2);     // 12 MB
    u16*   oT   = (u16*)alloc((size_t)D * E * 2);      // 4 MB
    u16*   w1T  = (u16*)alloc((size_t)F * D * 2);      // 8 MB
    u16*   w2T  = (u16*)alloc((size_t)D * F * 2);      // 8 MB
    float* bcat = (float*)alloc((size_t)E3 * 4);
    u16*   xn   = (u16*)alloc((size_t)BN * D * 2);     // 8 MB (reused as xn2)
    u16*   QKV  = (u16*)alloc((size_t)BN * E3 * 2);    // 48 MB (reused: P, h)
    u16*   Vt   = (u16*)alloc((size_t)Bb * E * N * 2); // 16 MB (reused as x2 fp32)
    u16*   Amat = (u16*)alloc((size_t)Bb * N * N * 2); // 32 MB (reused as parts)
    float* den  = (float*)alloc((size_t)BN * 4);

    u16*   xn2 = xn;
    u16*   P   = QKV;                  // [BN,E] bf16
    u16*   h   = QKV + (size_t)8 * 1024 * 1024;  // [BN,F] bf16
    float* x2  = (float*)Vt;           // [BN,D] fp32
    float* pt0 = (float*)Amat;         // split-K partial 0
    float* pt1 = pt0 + (size_t)BN * D; // split-K partial 1

    dim3 blk(256);

    // ---- prep: biases + den zero ----
    prep<<<dim3((BN + 255) / 256), blk, 0, stream>>>(q_b, k_b, v_b, bcat, den, E, BN);

    // ---- all weight transposes, one dispatch ----
    transpose_all<<<dim3(4096, 6), blk, 0, stream>>>(
        q_w, k_w, v_w, o_w, w1, w2, qkvT, oT, w1T, w2T);

    // ---- LN1 ----
    ln_bf16<<<BN, blk, 0, stream>>>(x, ln1g, ln1b, xn, D);

    // ---- fused QKV projection: [BN,3E], elu+1 on Q,K cols (BK=64) ----
    gemm_nt<EPI_QKV, 64><<<dim3(E3 / 128, BN / 128, 1), blk, 0, stream>>>(
        xn, qkvT, QKV, bcat, nullptr, BN, E3, D, D, D, 0, 0, 0, 0);

    // ---- V^T per batch: [N,E] (stride 3E) -> [E,N] ----
    transpose_u16<<<dim3(E / 32, N / 32, Bb), blk, 0, stream>>>(
        QKV + 2 * E, Vt, N, E, E3, (ll)N * E3, (ll)E * N);

    // ---- A = tril(Q K^T) per batch, fused rowsum -> den (BK=64) ----
    gemm_nt<EPI_TRIL, 64><<<dim3(N / 128, N / 128, Bb), blk, 0, stream>>>(
        QKV, QKV + E, Amat, nullptr, den, N, N, E, E3, E3,
        (ll)N * E3, (ll)N * E3, (ll)N * N, (ll)N);

    // ---- P = (A @ V) / den (triangular K-loop, BK=64) ----
    gemm_nt<EPI_DIV, 64><<<dim3(E / 128, N / 128, Bb), blk, 0, stream>>>(
        Amat, Vt, P, nullptr, den, N, E, N, N, N,
        (ll)N * N, (ll)E * N, (ll)N * E, (ll)N);

    // ---- split-K=2: parts = P @ o_w (fp32), BK=64 ----
    gemm_nt<EPI_PART, 64><<<dim3(D / 128, BN / 128, 2), blk, 0, stream>>>(
        P, oT, pt0, nullptr, nullptr, BN, D, E / 2, E, E,
        (ll)(E / 2), (ll)(E / 2), (ll)BN * D, 0);

    // ---- x2 = x + p0 + p1 + o_b ; xn2 = LN2(x2) ----
    combine_ln<<<BN, blk, 0, stream>>>(x, pt0, pt1, o_b, ln2g, ln2b, x2, xn2);

    // ---- h = gelu(xn2 @ w1 + b1) (BK=64) ----
    gemm_nt<EPI_GELU, 64><<<dim3(F / 128, BN / 128, 1), blk, 0, stream>>>(
        xn2, w1T, h, b1, nullptr, BN, F, D, D, D, 0, 0, 0, 0);

    // ---- split-K=2: parts = h @ w2 (fp32), BK=64 ----
    gemm_nt<EPI_PART, 64><<<dim3(D / 128, BN / 128, 2), blk, 0, stream>>>(
        h, w2T, pt0, nullptr, nullptr, BN, D, F / 2, F, F,
        (ll)(F / 2), (ll)(F / 2), (ll)BN * D, 0);

    // ---- out = x2 + p0 + p1 + b2 ----
    combine_out<<<dim3(BN * D / 4 / 256), blk, 0, stream>>>(x2, pt0, pt1, b2, out);
}